// Round 1
// baseline (532.960 us; speedup 1.0000x reference)
//
#include <hip/hip_runtime.h>

// SIRcell: B=4, N=5000, mob is (B,N,N) f32 = 400 MB — memory-bound.
// One-pass over mob computing BOTH einsums:
//   rowsum[b,i] = sum_j mob[b,i,j] * Iv[b,j]
//   colsum[b,j] = sum_i mob[b,i,j] * (Iv[b,i]/pop[b,i])
// Phase 1: block = (partial k, batch b); rows i = k + P*r. Threads own fixed
// column slices (float4), accumulate colsum in REGISTERS (exclusive ownership,
// no atomics), write per-block partials to ws. Rowsum via wave shuffle reduce.
// Phase 2: reduce P partials per column + epilogue + float4 store of (B,N,4).

constexpr int B  = 4;
constexpr int N  = 5000;
constexpr int NT = 256;   // phase-1 threads/block
// column ownership: thread t owns j4 = 4*t + 1024*kk, kk=0..4 (kk==4 only t<226)

__global__ __launch_bounds__(NT) void sir_phase1(
    const float* __restrict__ mob, const float* __restrict__ SIR,
    float* __restrict__ ws_row, float* __restrict__ ws_col, int P)
{
    const int b = blockIdx.y;
    const int k = blockIdx.x;          // partial index; rows i = k + P*r
    const int t = threadIdx.x;

    __shared__ float red[316][4];      // per-(row,wave) partials; P>=16 -> <=313 rows

    const float* sir_b = SIR + (size_t)b * N * 3;

    // Load Iv for owned columns into registers (Iv[j] = SIR[b,j,1], stride-3)
    float4 iv[5];
    #pragma unroll
    for (int kk = 0; kk < 5; ++kk) {
        const int j4 = 4 * t + 1024 * kk;
        if (kk < 4 || t < 226) {
            iv[kk].x = sir_b[(j4 + 0) * 3 + 1];
            iv[kk].y = sir_b[(j4 + 1) * 3 + 1];
            iv[kk].z = sir_b[(j4 + 2) * 3 + 1];
            iv[kk].w = sir_b[(j4 + 3) * 3 + 1];
        } else {
            iv[kk] = make_float4(0.f, 0.f, 0.f, 0.f);
        }
    }

    float4 col[5];
    #pragma unroll
    for (int kk = 0; kk < 5; ++kk) col[kk] = make_float4(0.f, 0.f, 0.f, 0.f);

    const float* mob_b = mob + (size_t)b * N * N;

    int r = 0;
    for (int i = k; i < N; i += P, ++r) {
        const float s  = sir_b[i * 3 + 0];
        const float ii = sir_b[i * 3 + 1];
        const float rr = sir_b[i * 3 + 2];
        const float w  = ii / (s + ii + rr);   // Iv[i]/pop[i]

        const float* mrow = mob_b + (size_t)i * N;
        float rp = 0.f;
        #pragma unroll
        for (int kk = 0; kk < 4; ++kk) {
            const float4 m = *reinterpret_cast<const float4*>(mrow + 4 * t + 1024 * kk);
            rp = fmaf(m.x, iv[kk].x, rp);
            rp = fmaf(m.y, iv[kk].y, rp);
            rp = fmaf(m.z, iv[kk].z, rp);
            rp = fmaf(m.w, iv[kk].w, rp);
            col[kk].x = fmaf(m.x, w, col[kk].x);
            col[kk].y = fmaf(m.y, w, col[kk].y);
            col[kk].z = fmaf(m.z, w, col[kk].z);
            col[kk].w = fmaf(m.w, w, col[kk].w);
        }
        if (t < 226) {
            const float4 m = *reinterpret_cast<const float4*>(mrow + 4 * t + 4096);
            rp = fmaf(m.x, iv[4].x, rp);
            rp = fmaf(m.y, iv[4].y, rp);
            rp = fmaf(m.z, iv[4].z, rp);
            rp = fmaf(m.w, iv[4].w, rp);
            col[4].x = fmaf(m.x, w, col[4].x);
            col[4].y = fmaf(m.y, w, col[4].y);
            col[4].z = fmaf(m.z, w, col[4].z);
            col[4].w = fmaf(m.w, w, col[4].w);
        }
        // wave64 reduction of the row-dot partial
        #pragma unroll
        for (int off = 32; off > 0; off >>= 1)
            rp += __shfl_xor(rp, off, 64);
        if ((t & 63) == 0) red[r][t >> 6] = rp;
    }
    __syncthreads();

    // write rowsums (r is wave-uniform: number of rows this block processed)
    for (int q = t; q < r; q += NT) {
        const int i = k + P * q;
        ws_row[(size_t)b * N + i] = red[q][0] + red[q][1] + red[q][2] + red[q][3];
    }

    // write this block's column partials (coalesced float4)
    float* cp = ws_col + ((size_t)b * P + k) * N;
    #pragma unroll
    for (int kk = 0; kk < 4; ++kk)
        *reinterpret_cast<float4*>(cp + 4 * t + 1024 * kk) = col[kk];
    if (t < 226)
        *reinterpret_cast<float4*>(cp + 4 * t + 4096) = col[4];
}

__global__ __launch_bounds__(256) void sir_phase2(
    const float* __restrict__ ws_row, const float* __restrict__ ws_col,
    const float* __restrict__ SIR, const float* __restrict__ pb,
    const float* __restrict__ pg, float* __restrict__ out, int P)
{
    const int b = blockIdx.y;
    const int j = blockIdx.x * 256 + threadIdx.x;
    if (j >= N) return;

    const float* base = ws_col + (size_t)b * P * N + j;
    float cs = 0.f;
    #pragma unroll 8
    for (int p = 0; p < P; ++p) cs += base[(size_t)p * N];

    const float s  = SIR[((size_t)b * N + j) * 3 + 0];
    const float ii = SIR[((size_t)b * N + j) * 3 + 1];
    const float rr = SIR[((size_t)b * N + j) * 3 + 2];
    const float pop = s + ii + rr;
    const float tr = ws_row[(size_t)b * N + j] / pop;   // term_row
    const float inew = pb[b] * (cs + tr);               // param_b * propagation
    const float ig = ii * pg[b];

    float4 o;
    o.x = inew;            // I_new
    o.y = s - inew;        // S_t
    o.z = ii + inew - ig;  // I_t
    o.w = ig + rr;         // R_t
    *reinterpret_cast<float4*>(out + ((size_t)b * N + j) * 4) = o;
}

extern "C" void kernel_launch(void* const* d_in, const int* in_sizes, int n_in,
                              void* d_out, int out_size, void* d_ws, size_t ws_size,
                              hipStream_t stream)
{
    const float* pb  = (const float*)d_in[0];
    const float* pg  = (const float*)d_in[1];
    const float* mob = (const float*)d_in[2];
    const float* SIR = (const float*)d_in[3];
    float* out = (float*)d_out;
    float* ws  = (float*)d_ws;

    // partials per batch; shrink if workspace is small (needs (B*N + B*P*N)*4 bytes)
    int P = 128;
    while (P > 16 && ((size_t)B * N + (size_t)B * P * N) * 4 > ws_size) P >>= 1;

    float* ws_row = ws;            // B*N floats
    float* ws_col = ws + B * N;    // B*P*N floats

    sir_phase1<<<dim3(P, B), NT, 0, stream>>>(mob, SIR, ws_row, ws_col, P);
    sir_phase2<<<dim3((N + 255) / 256, B), 256, 0, stream>>>(
        ws_row, ws_col, SIR, pb, pg, out, P);
}

// Round 3
// 515.143 us; speedup vs baseline: 1.0346x; 1.0346x over previous
//
#include <hip/hip_runtime.h>

// SIRcell: B=4, N=5000, mob (B,N,N) f32 = 400 MB — memory-bound, mob read ONCE.
// One pass computes BOTH einsums:
//   rowsum[b,i] = sum_j mob[b,i,j] * Iv[b,j]
//   colsum[b,j] = sum_i mob[b,i,j] * (Iv[b,i]/pop[b,i])
// Phase 1: grid (P=256 partials × B). Block k handles rows i ≡ k (mod P);
// threads own fixed column float4 slices -> colsum partials live in REGISTERS
// (exclusive ownership, no atomics). Rowsum via wave shuffle reduce.
// 1024 blocks = 4 blocks/CU = 16 waves/CU (was 2/CU — latency-hiding fix).
// Phase 2: reduce P column partials + epilogue + float4 store of (B,N,4).

constexpr int B  = 4;
constexpr int N  = 5000;
constexpr int NT = 256;       // phase-1 threads/block
constexpr int ROWS_MAX = 80;  // supports P >= 64

typedef float f32x4 __attribute__((ext_vector_type(4)));

__global__ __launch_bounds__(NT, 4) void sir_phase1(
    const float* __restrict__ mob, const float* __restrict__ SIR,
    float* __restrict__ ws_row, float* __restrict__ ws_col, int P)
{
    const int b = blockIdx.y;
    const int k = blockIdx.x;          // partial index; rows i = k + P*r
    const int t = threadIdx.x;

    __shared__ float red[ROWS_MAX][4]; // per-(row,wave) rowsum partials (1.3 KB)

    const float* sir_b = SIR + (size_t)b * N * 3;

    // Iv for owned columns (Iv[j] = SIR[b,j,1], stride-3) -> registers
    f32x4 iv[5];
    #pragma unroll
    for (int kk = 0; kk < 5; ++kk) {
        const int j4 = 4 * t + 1024 * kk;
        if (kk < 4 || t < 226) {
            iv[kk][0] = sir_b[(j4 + 0) * 3 + 1];
            iv[kk][1] = sir_b[(j4 + 1) * 3 + 1];
            iv[kk][2] = sir_b[(j4 + 2) * 3 + 1];
            iv[kk][3] = sir_b[(j4 + 3) * 3 + 1];
        } else {
            iv[kk] = (f32x4)0.f;
        }
    }

    f32x4 col[5];
    #pragma unroll
    for (int kk = 0; kk < 5; ++kk) col[kk] = (f32x4)0.f;

    const float* mob_b = mob + (size_t)b * N * N;

    int r = 0;
    for (int i = k; i < N; i += P, ++r) {
        const float s  = sir_b[i * 3 + 0];
        const float ii = sir_b[i * 3 + 1];
        const float rr = sir_b[i * 3 + 2];
        const float w  = ii / (s + ii + rr);   // Iv[i]/pop[i]

        const float* mrow = mob_b + (size_t)i * N;
        float rp = 0.f;
        #pragma unroll
        for (int kk = 0; kk < 4; ++kk) {
            const f32x4 m = __builtin_nontemporal_load(
                reinterpret_cast<const f32x4*>(mrow + 4 * t + 1024 * kk));
            rp = fmaf(m[0], iv[kk][0], rp);
            rp = fmaf(m[1], iv[kk][1], rp);
            rp = fmaf(m[2], iv[kk][2], rp);
            rp = fmaf(m[3], iv[kk][3], rp);
            col[kk][0] = fmaf(m[0], w, col[kk][0]);
            col[kk][1] = fmaf(m[1], w, col[kk][1]);
            col[kk][2] = fmaf(m[2], w, col[kk][2]);
            col[kk][3] = fmaf(m[3], w, col[kk][3]);
        }
        if (t < 226) {
            const f32x4 m = __builtin_nontemporal_load(
                reinterpret_cast<const f32x4*>(mrow + 4 * t + 4096));
            rp = fmaf(m[0], iv[4][0], rp);
            rp = fmaf(m[1], iv[4][1], rp);
            rp = fmaf(m[2], iv[4][2], rp);
            rp = fmaf(m[3], iv[4][3], rp);
            col[4][0] = fmaf(m[0], w, col[4][0]);
            col[4][1] = fmaf(m[1], w, col[4][1]);
            col[4][2] = fmaf(m[2], w, col[4][2]);
            col[4][3] = fmaf(m[3], w, col[4][3]);
        }
        // wave64 butterfly reduce of the row-dot partial
        #pragma unroll
        for (int off = 32; off > 0; off >>= 1)
            rp += __shfl_xor(rp, off, 64);
        if ((t & 63) == 0) red[r][t >> 6] = rp;
    }
    __syncthreads();

    // rowsums (r is block-uniform: rows processed by this block)
    for (int q = t; q < r; q += NT) {
        const int i = k + P * q;
        ws_row[(size_t)b * N + i] = red[q][0] + red[q][1] + red[q][2] + red[q][3];
    }

    // column partials (coalesced float4)
    float* cp = ws_col + ((size_t)b * P + k) * N;
    #pragma unroll
    for (int kk = 0; kk < 4; ++kk)
        *reinterpret_cast<f32x4*>(cp + 4 * t + 1024 * kk) = col[kk];
    if (t < 226)
        *reinterpret_cast<f32x4*>(cp + 4 * t + 4096) = col[4];
}

__global__ __launch_bounds__(256) void sir_phase2(
    const float* __restrict__ ws_row, const float* __restrict__ ws_col,
    const float* __restrict__ SIR, const float* __restrict__ pb,
    const float* __restrict__ pg, float* __restrict__ out, int P)
{
    const int b = blockIdx.y;
    const int j = blockIdx.x * 256 + threadIdx.x;
    if (j >= N) return;

    const float* base = ws_col + (size_t)b * P * N + j;
    float cs = 0.f;
    #pragma unroll 8
    for (int p = 0; p < P; ++p) cs += base[(size_t)p * N];

    const float s  = SIR[((size_t)b * N + j) * 3 + 0];
    const float ii = SIR[((size_t)b * N + j) * 3 + 1];
    const float rr = SIR[((size_t)b * N + j) * 3 + 2];
    const float pop = s + ii + rr;
    const float tr = ws_row[(size_t)b * N + j] / pop;   // term_row
    const float inew = pb[b] * (cs + tr);               // param_b * propagation
    const float ig = ii * pg[b];

    f32x4 o;
    o[0] = inew;            // I_new
    o[1] = s - inew;        // S_t
    o[2] = ii + inew - ig;  // I_t
    o[3] = ig + rr;         // R_t
    *reinterpret_cast<f32x4*>(out + ((size_t)b * N + j) * 4) = o;
}

extern "C" void kernel_launch(void* const* d_in, const int* in_sizes, int n_in,
                              void* d_out, int out_size, void* d_ws, size_t ws_size,
                              hipStream_t stream)
{
    const float* pb  = (const float*)d_in[0];
    const float* pg  = (const float*)d_in[1];
    const float* mob = (const float*)d_in[2];
    const float* SIR = (const float*)d_in[3];
    float* out = (float*)d_out;
    float* ws  = (float*)d_ws;

    // partials per batch; shrink if workspace is small (needs (B*N + B*P*N)*4 B)
    int P = 256;
    while (P > 64 && ((size_t)B * N + (size_t)B * P * N) * 4 > ws_size) P >>= 1;

    float* ws_row = ws;            // B*N floats
    float* ws_col = ws + B * N;    // B*P*N floats

    sir_phase1<<<dim3(P, B), NT, 0, stream>>>(mob, SIR, ws_row, ws_col, P);
    sir_phase2<<<dim3((N + 255) / 256, B), 256, 0, stream>>>(
        ws_row, ws_col, SIR, pb, pg, out, P);
}